// Round 8
// baseline (66.855 us; speedup 1.0000x reference)
//
#include <hip/hip_runtime.h>

#define WIN   11
#define IW    512
#define IH    512
#define OW    502         // 512 - 10
#define OH    502
#define NCH   48          // 16*3 channel-images
#define TW    118         // output tile width (valid cols per tile)
#define TH    8           // output tile height
#define SWC   128         // columns computed in V: TW + 10 = 128 = one col per thread
#define SWP   134         // LDS row stride in v2f units: 268 dw % 32 = 12 -> 2-way max
#define SROWS 18          // TH + WIN - 1
#define NGX   5           // ceil(502/118)
#define NGY   63          // ceil(502/8)

typedef float v2f __attribute__((ext_vector_type(2)));

__device__ __forceinline__ float fast_rcp(float x) {
    return __builtin_amdgcn_rcpf(x);   // v_rcp_f32, ~1 ulp
}

// ---- V phase: one streaming step (input row J), all indices compile-time ----
template<bool EDGE, int J>
__device__ __forceinline__ void vstep(const float* __restrict__ p1,
                                      const float* __restrict__ p2,
                                      int y0, int gx,
                                      v2f (&accA)[TH], v2f (&accB)[TH],
                                      const float (&w)[WIN])
{
    int gy = y0 + J;
    if (EDGE) gy = min(gy, IH - 1);
    const int gidx = gy * IW + gx;
    const float av = p1[gidx];
    const float bv = p2[gidx];
    v2f ab; ab.x = av; ab.y = bv;                         // (a, b)
    v2f st; st.x = fmaf(av, av, bv * bv); st.y = av * bv; // (a^2+b^2, ab)
#pragma unroll
    for (int k = 0; k < WIN; ++k) {
        const int r = J - k;                              // compile-time after unroll
        if (r >= 0 && r < TH) {
            v2f ws; ws.x = w[k]; ws.y = w[k];
            accA[r] = __builtin_elementwise_fma(ws, ab, accA[r]);
            accB[r] = __builtin_elementwise_fma(ws, st, accB[r]);
        }
    }
}

template<bool EDGE, int J>
struct VRec {
    static __device__ __forceinline__ void run(const float* __restrict__ p1,
                                               const float* __restrict__ p2,
                                               int y0, int gx,
                                               v2f (&accA)[TH], v2f (&accB)[TH],
                                               const float (&w)[WIN])
    {
        vstep<EDGE, J>(p1, p2, y0, gx, accA, accB, w);
        VRec<EDGE, J + 1>::run(p1, p2, y0, gx, accA, accB, w);
    }
};
template<bool EDGE>
struct VRec<EDGE, SROWS> {
    static __device__ __forceinline__ void run(const float* __restrict__,
                                               const float* __restrict__,
                                               int, int, v2f (&)[TH], v2f (&)[TH],
                                               const float (&)[WIN]) {}
};

template<bool EDGE>
__device__ __forceinline__ void ssim_tile(const float* __restrict__ p1,
                                          const float* __restrict__ p2,
                                          const float (&w)[WIN],
                                          v2f (*vbuf)[TH][SWP],
                                          int x0, int y0, int tid, float& acc)
{
    // ---- Phase V: streaming vertical blur; ALL 128 threads, one column each.
    {
        const int c = tid;                 // 0..127
        int gx = x0 + c;
        if (EDGE) gx = min(gx, IW - 1);
        v2f accA[TH], accB[TH];
#pragma unroll
        for (int r = 0; r < TH; ++r) {
            accA[r] = (v2f){0.f, 0.f};
            accB[r] = (v2f){0.f, 0.f};
        }
        VRec<EDGE, 0>::run(p1, p2, y0, gx, accA, accB, w);
#pragma unroll
        for (int r = 0; r < TH; ++r) {
            vbuf[0][r][c] = accA[r];
            vbuf[1][r][c] = accB[r];
        }
    }
    __syncthreads();

    // ---- Phase H: horizontal blur + SSIM. Thread = (row r, x-group g of 8 px).
    const int r  = tid & 7;      // 0..7
    const int g  = tid >> 3;     // 0..15
    const int xs = g * 8;

    if (g < 15) {                // 15 groups cover px 0..119 >= TW=118; g=15 would OOB
        v2f resA[8], resB[8];
#pragma unroll
        for (int q = 0; q < 2; ++q) {
            v2f x2[18];
            const float4* src = reinterpret_cast<const float4*>(&vbuf[q][r][xs]);
#pragma unroll
            for (int t = 0; t < 9; ++t) {
                float4 f = src[t];
                x2[2*t+0].x = f.x; x2[2*t+0].y = f.y;
                x2[2*t+1].x = f.z; x2[2*t+1].y = f.w;
            }
#pragma unroll
            for (int o = 0; o < 8; ++o) {
                v2f s = {0.f, 0.f};
#pragma unroll
                for (int k = 0; k < WIN; ++k) {
                    v2f ws; ws.x = w[k]; ws.y = w[k];
                    s = __builtin_elementwise_fma(ws, x2[o + k], s);
                }
                if (q == 0) resA[o] = s; else resB[o] = s;
            }
        }

        const float c1 = 0.0001f;   // (0.01*1.0)^2
        const float c2 = 0.0009f;   // (0.03*1.0)^2
        const int oy = y0 + r;
#pragma unroll
        for (int o = 0; o < 8; ++o) {
            const int tc = xs + o;                 // tile-local column
            bool valid = (tc < TW);                // don't emit neighbor tile's px
            if (EDGE) valid = valid && (oy < OH) && ((x0 + tc) < OW);
            if (valid) {
                float m1 = resA[o].x, m2 = resA[o].y;
                float mu11 = m1 * m1, mu22 = m2 * m2, mu12 = m1 * m2;
                float sAB = resB[o].x - mu11 - mu22;   // s11 + s22
                float s12 = resB[o].y - mu12;
                float num = (2.f * mu12 + c1) * (2.f * s12 + c2);
                float den = (mu11 + mu22 + c1) * (sAB + c2);
                acc += num * fast_rcp(den);
            }
        }
    }
}

// Grid: x = 5 x-tiles, y = 63 y-tiles, z = 48 channel-images; 128-thread blocks
__global__ __launch_bounds__(128, 4)
void ssim_fused_kernel(const float* __restrict__ img1,
                       const float* __restrict__ img2,
                       const float* __restrict__ win,
                       float* __restrict__ partial)
{
    __shared__ __align__(16) v2f vbuf[2][TH][SWP];   // 17,152 B -> 9 blocks/CU
    __shared__ float wavesum[2];

    const int tid = threadIdx.x;
    const int ch = blockIdx.z;
    const int x0 = blockIdx.x * TW;
    const int y0 = blockIdx.y * TH;
    const float* __restrict__ p1 = img1 + (size_t)ch * (IW * IH);
    const float* __restrict__ p2 = img2 + (size_t)ch * (IW * IH);

    float w[WIN];
#pragma unroll
    for (int k = 0; k < WIN; ++k) w[k] = win[k];

    float acc = 0.f;
    const bool edge = (blockIdx.x == gridDim.x - 1) || (blockIdx.y == gridDim.y - 1);
    if (edge) ssim_tile<true >(p1, p2, w, vbuf, x0, y0, tid, acc);
    else      ssim_tile<false>(p1, p2, w, vbuf, x0, y0, tid, acc);

    // ---- block reduction (wave64 shuffle, then 2 wave leaders)
#pragma unroll
    for (int off = 32; off > 0; off >>= 1)
        acc += __shfl_down(acc, off, 64);
    if ((tid & 63) == 0) wavesum[tid >> 6] = acc;
    __syncthreads();
    if (tid == 0) {
        partial[(size_t)blockIdx.z * (gridDim.x * gridDim.y)
                + blockIdx.y * gridDim.x + blockIdx.x] = wavesum[0] + wavesum[1];
    }
}

__global__ __launch_bounds__(256)
void reduce_partials_kernel(const float* __restrict__ partial, int n,
                            float* __restrict__ out, double inv_count)
{
    __shared__ double sd[256];
    double s = 0.0;
    for (int i = threadIdx.x; i < n; i += 256)
        s += (double)partial[i];
    sd[threadIdx.x] = s;
    __syncthreads();
    for (int off = 128; off > 0; off >>= 1) {
        if (threadIdx.x < off) sd[threadIdx.x] += sd[threadIdx.x + off];
        __syncthreads();
    }
    if (threadIdx.x == 0)
        out[0] = (float)(sd[0] * inv_count);
}

extern "C" void kernel_launch(void* const* d_in, const int* in_sizes, int n_in,
                              void* d_out, int out_size, void* d_ws, size_t ws_size,
                              hipStream_t stream)
{
    const float* img1 = (const float*)d_in[0];
    const float* img2 = (const float*)d_in[1];
    const float* win  = (const float*)d_in[2];
    float* out = (float*)d_out;
    float* partial = (float*)d_ws;

    dim3 grid(NGX, NGY, NCH);            // 5 x 63 x 48 = 15120 blocks
    dim3 block(128);

    ssim_fused_kernel<<<grid, block, 0, stream>>>(img1, img2, win, partial);

    const int nblocks = NGX * NGY * NCH;
    const double inv_count = 1.0 / ((double)NCH * OW * OH);
    reduce_partials_kernel<<<1, 256, 0, stream>>>(partial, nblocks, out, inv_count);
}

// Round 9
// 49.876 us; speedup vs baseline: 1.3404x; 1.3404x over previous
//
#include <hip/hip_runtime.h>

#define WIN   11
#define IW    512
#define IH    512
#define OW    502         // 512 - 10
#define OH    502
#define NCH   48          // 16*3 channel-images
#define TW    118         // output tile width (valid cols per tile)
#define SWC   128         // columns computed in V: TW + 10 = one col per thread
#define SWP   134         // LDS row stride in v2f units: 268 dw % 32 = 12 -> 2-way max
#define CH    8           // chunk height (output rows per chunk)
#define NCHUNK 4          // chunks per slab
#define SLABH (CH*NCHUNK) // 32 output rows per block
#define NGX   5           // ceil(502/118)
#define NGY   16          // ceil(502/32)

typedef float v2f __attribute__((ext_vector_type(2)));

__device__ __forceinline__ float fast_rcp(float x) {
    return __builtin_amdgcn_rcpf(x);   // v_rcp_f32, ~1 ulp
}

template<bool EDGE>
__device__ __forceinline__ void ssim_slab(const float* __restrict__ p1,
                                          const float* __restrict__ p2,
                                          const float (&w)[WIN],
                                          v2f (*vbuf)[CH][SWP],
                                          int x0, int y0, int tid, float& acc)
{
    // ---- V mapping: one column per thread (all 128 threads dense).
    const int c = tid;                  // 0..127
    int gx = x0 + c;
    if (EDGE) gx = min(gx, IW - 1);

    // 10-row (a,b) register history: input rows y0 .. y0+9
    v2f h[10];
#pragma unroll
    for (int j = 0; j < 10; ++j) {
        int gy = y0 + j; if (EDGE) gy = min(gy, IH - 1);
        const int gidx = gy * IW + gx;
        h[j].x = p1[gidx];
        h[j].y = p2[gidx];
    }

    // ---- H mapping: row-in-chunk r, x-group g of 8 px
    const int rh = tid & 7;             // 0..7
    const int g  = tid >> 3;            // 0..15
    const int xs = g * 8;
    const float c1 = 0.0001f;           // (0.01*1.0)^2
    const float c2 = 0.0009f;           // (0.03*1.0)^2

#pragma unroll
    for (int ci = 0; ci < NCHUNK; ++ci) {
        // ---- load this chunk's 8 new input rows (batched issue)
        const int jbase = y0 + 10 + ci * CH;
        v2f n[CH];
#pragma unroll
        for (int j = 0; j < CH; ++j) {
            int gy = jbase + j; if (EDGE) gy = min(gy, IH - 1);
            const int gidx = gy * IW + gx;
            n[j].x = p1[gidx];
            n[j].y = p2[gidx];
        }

        // ---- vertical blur: 18-row window = h[0..9] ++ n[0..7]
        v2f accA[CH], accB[CH];
#pragma unroll
        for (int r = 0; r < CH; ++r) {
            accA[r] = (v2f){0.f, 0.f};
            accB[r] = (v2f){0.f, 0.f};
        }
#pragma unroll
        for (int j = 0; j < CH + 10; ++j) {
            v2f ab = (j < 10) ? h[j] : n[j - 10];
            v2f st;
            st.x = fmaf(ab.x, ab.x, ab.y * ab.y);   // a^2 + b^2
            st.y = ab.x * ab.y;                     // a*b
#pragma unroll
            for (int k = 0; k < WIN; ++k) {
                const int r = j - k;                // compile-time after unroll
                if (r >= 0 && r < CH) {
                    v2f ws; ws.x = w[k]; ws.y = w[k];
                    accA[r] = __builtin_elementwise_fma(ws, ab, accA[r]);
                    accB[r] = __builtin_elementwise_fma(ws, st, accB[r]);
                }
            }
        }
#pragma unroll
        for (int r = 0; r < CH; ++r) {
            vbuf[0][r][c] = accA[r];
            vbuf[1][r][c] = accB[r];
        }
        // ---- history shift: keep last 10 window rows (j=0,1 read old h before write)
#pragma unroll
        for (int j = 0; j < 10; ++j)
            h[j] = (j < 2) ? h[8 + j] : n[j - 2];

        __syncthreads();

        // ---- H phase on this chunk
        if (g < 15) {                   // 15 groups cover px 0..119 >= TW
            v2f resA[8], resB[8];
#pragma unroll
            for (int q = 0; q < 2; ++q) {
                v2f x2[18];
                const float4* src = reinterpret_cast<const float4*>(&vbuf[q][rh][xs]);
#pragma unroll
                for (int t = 0; t < 9; ++t) {
                    float4 f = src[t];
                    x2[2*t+0].x = f.x; x2[2*t+0].y = f.y;
                    x2[2*t+1].x = f.z; x2[2*t+1].y = f.w;
                }
#pragma unroll
                for (int o = 0; o < 8; ++o) {
                    v2f s = {0.f, 0.f};
#pragma unroll
                    for (int k = 0; k < WIN; ++k) {
                        v2f ws; ws.x = w[k]; ws.y = w[k];
                        s = __builtin_elementwise_fma(ws, x2[o + k], s);
                    }
                    if (q == 0) resA[o] = s; else resB[o] = s;
                }
            }

            const int oy = y0 + ci * CH + rh;
#pragma unroll
            for (int o = 0; o < 8; ++o) {
                const int tc = xs + o;             // tile-local column
                bool valid = (tc < TW);
                if (EDGE) valid = valid && (oy < OH) && ((x0 + tc) < OW);
                if (valid) {
                    float m1 = resA[o].x, m2 = resA[o].y;
                    float mu11 = m1 * m1, mu22 = m2 * m2, mu12 = m1 * m2;
                    float sAB = resB[o].x - mu11 - mu22;   // s11 + s22
                    float s12 = resB[o].y - mu12;
                    float num = (2.f * mu12 + c1) * (2.f * s12 + c2);
                    float den = (mu11 + mu22 + c1) * (sAB + c2);
                    acc += num * fast_rcp(den);
                }
            }
        }
        __syncthreads();                // protect vbuf before next chunk's V writes
    }
}

// Grid: x = 5 x-tiles, y = 16 y-slabs, z = 48 channel-images; 128-thread blocks
__global__ __launch_bounds__(128, 4)
void ssim_fused_kernel(const float* __restrict__ img1,
                       const float* __restrict__ img2,
                       const float* __restrict__ win,
                       float* __restrict__ partial)
{
    __shared__ __align__(16) v2f vbuf[2][CH][SWP];   // 17,152 B -> 9 blocks/CU
    __shared__ float wavesum[2];

    const int tid = threadIdx.x;
    const int ch = blockIdx.z;
    const int x0 = blockIdx.x * TW;
    const int y0 = blockIdx.y * SLABH;
    const float* __restrict__ p1 = img1 + (size_t)ch * (IW * IH);
    const float* __restrict__ p2 = img2 + (size_t)ch * (IW * IH);

    float w[WIN];
#pragma unroll
    for (int k = 0; k < WIN; ++k) w[k] = win[k];

    float acc = 0.f;
    const bool edge = (blockIdx.x == gridDim.x - 1) || (blockIdx.y == gridDim.y - 1);
    if (edge) ssim_slab<true >(p1, p2, w, vbuf, x0, y0, tid, acc);
    else      ssim_slab<false>(p1, p2, w, vbuf, x0, y0, tid, acc);

    // ---- block reduction (wave64 shuffle, then 2 wave leaders)
#pragma unroll
    for (int off = 32; off > 0; off >>= 1)
        acc += __shfl_down(acc, off, 64);
    if ((tid & 63) == 0) wavesum[tid >> 6] = acc;
    __syncthreads();
    if (tid == 0) {
        partial[(size_t)blockIdx.z * (gridDim.x * gridDim.y)
                + blockIdx.y * gridDim.x + blockIdx.x] = wavesum[0] + wavesum[1];
    }
}

__global__ __launch_bounds__(256)
void reduce_partials_kernel(const float* __restrict__ partial, int n4,
                            float* __restrict__ out, double inv_count)
{
    __shared__ double sd[256];
    const float4* p4 = reinterpret_cast<const float4*>(partial);
    double s = 0.0;
    for (int i = threadIdx.x; i < n4; i += 256) {
        float4 f = p4[i];
        s += (double)f.x + (double)f.y + (double)f.z + (double)f.w;
    }
    sd[threadIdx.x] = s;
    __syncthreads();
    for (int off = 128; off > 0; off >>= 1) {
        if (threadIdx.x < off) sd[threadIdx.x] += sd[threadIdx.x + off];
        __syncthreads();
    }
    if (threadIdx.x == 0)
        out[0] = (float)(sd[0] * inv_count);
}

extern "C" void kernel_launch(void* const* d_in, const int* in_sizes, int n_in,
                              void* d_out, int out_size, void* d_ws, size_t ws_size,
                              hipStream_t stream)
{
    const float* img1 = (const float*)d_in[0];
    const float* img2 = (const float*)d_in[1];
    const float* win  = (const float*)d_in[2];
    float* out = (float*)d_out;
    float* partial = (float*)d_ws;

    dim3 grid(NGX, NGY, NCH);            // 5 x 16 x 48 = 3840 blocks
    dim3 block(128);

    ssim_fused_kernel<<<grid, block, 0, stream>>>(img1, img2, win, partial);

    const int nblocks = NGX * NGY * NCH; // 3840, divisible by 4
    const double inv_count = 1.0 / ((double)NCH * OW * OH);
    reduce_partials_kernel<<<1, 256, 0, stream>>>(partial, nblocks / 4, out, inv_count);
}